// Round 5
// baseline (299.033 us; speedup 1.0000x reference)
//
#include <hip/hip_runtime.h>
#include <cstdint>
#include <cstddef>

#define BB   32
#define NN   1024
#define FIN  128
#define FOUT 128

typedef __attribute__((ext_vector_type(8))) short bf16x8;
typedef __attribute__((ext_vector_type(4))) float f32x4;

__device__ __forceinline__ unsigned int f2bf(float f) {
    union { float f; unsigned int u; } v; v.f = f;
    unsigned int u = v.u;
    return (u + 0x7FFFu + ((u >> 16) & 1u)) >> 16;   // RNE fp32 -> bf16
}
__device__ __forceinline__ unsigned int pack2(float a, float b) {
    return f2bf(a) | (f2bf(b) << 16);
}

// ---------------------------------------------------------------------------
// Kernel 1: Y = node @ W^T, stored FRAGMENT-NATIVE for gcn's MFMA B operand:
//   Yt2[((b*32 + kc)*8 + ni)*64 + lane] (16B granules), where
//   lane = q*16 + lcol holds bf16 Y[o = ni*16+lcol][m = kc*32 + q*8 .. +7].
// Only the final store mapping changed vs the verified kernel — same bytes,
// different addresses. Store is fully coalesced (lane' = tid&63 -> +16B).
// ---------------------------------------------------------------------------
__global__ __launch_bounds__(256) void y_kernel(const float* __restrict__ node,
                                                const float* __restrict__ W,
                                                unsigned short* __restrict__ Yt) {
    __shared__ unsigned short Wlds[128 * 136];
    __shared__ unsigned short Nlds[64 * 136];

    const int tid = threadIdx.x;
    const int bid = blockIdx.x;
    const int b   = bid >> 4;
    const int m0  = (bid & 15) * 64;

    #pragma unroll
    for (int i = 0; i < 16; ++i) {
        const int idx = i * 256 + tid;
        const int row = idx >> 5;
        const int c   = (idx & 31) * 4;
        float4 v = ((const float4*)W)[idx];
        uint2 p; p.x = pack2(v.x, v.y); p.y = pack2(v.z, v.w);
        *(uint2*)&Wlds[row * 136 + c] = p;
    }
    {
        const float* base = node + ((size_t)b * NN + m0) * FIN;
        #pragma unroll
        for (int i = 0; i < 8; ++i) {
            const int idx = i * 256 + tid;
            const int row = idx >> 5;
            const int c   = (idx & 31) * 4;
            float4 v = *(const float4*)(base + row * FIN + c);
            uint2 p; p.x = pack2(v.x, v.y); p.y = pack2(v.z, v.w);
            *(uint2*)&Nlds[row * 136 + c] = p;
        }
    }
    __syncthreads();

    const int w = tid >> 6, lane = tid & 63;
    const int wo = w * 32;
    const int lcol = lane & 15, lk = (lane >> 4) * 8;

    f32x4 acc[2][4] = {};
    #pragma unroll
    for (int kc = 0; kc < 4; ++kc) {
        const int kof = kc * 32 + lk;
        bf16x8 a[2], bb[4];
        #pragma unroll
        for (int mi = 0; mi < 2; ++mi)
            a[mi] = *(const bf16x8*)&Wlds[(wo + mi*16 + lcol) * 136 + kof];
        #pragma unroll
        for (int ni = 0; ni < 4; ++ni)
            bb[ni] = *(const bf16x8*)&Nlds[(ni*16 + lcol) * 136 + kof];
        #pragma unroll
        for (int mi = 0; mi < 2; ++mi)
            #pragma unroll
            for (int ni = 0; ni < 4; ++ni)
                acc[mi][ni] = __builtin_amdgcn_mfma_f32_16x16x32_bf16(
                    a[mi], bb[ni], acc[mi][ni], 0, 0, 0);
    }
    __syncthreads();

    unsigned short* Ylds = Wlds;
    const int rq = (lane >> 4) * 4;
    #pragma unroll
    for (int mi = 0; mi < 2; ++mi)
        #pragma unroll
        for (int ni = 0; ni < 4; ++ni)
            #pragma unroll
            for (int r = 0; r < 4; ++r) {
                const int o = wo + mi * 16 + rq + r;
                const int m = ni * 16 + lcol;
                Ylds[o * 72 + m] = (unsigned short)f2bf(acc[mi][ni][r]);
            }
    __syncthreads();

    {
        // fragment-native store: thread (p=tid>>6, q2, lcol2) covers
        // (kcl,ni) pairs pr = p + 4j; lane' = q2*16+lcol2 = tid&63.
        const int lcol2 = tid & 15, q2 = (tid >> 4) & 3, p = tid >> 6;
        const int kc0 = m0 >> 5;
        #pragma unroll
        for (int j = 0; j < 4; ++j) {
            const int pr  = p + j * 4;            // 0..15
            const int kcl = pr >> 3;              // 0..1
            const int ni  = pr & 7;               // 0..7
            const int o    = ni * 16 + lcol2;
            const int mloc = kcl * 32 + q2 * 8;
            uint4 v = *(const uint4*)&Ylds[o * 72 + mloc];
            *(uint4*)(Yt + (((size_t)((b * 32 + kc0 + kcl) * 8 + ni)) * 64
                            + (tid & 63)) * 8) = v;
        }
    }
}

// ---------------------------------------------------------------------------
// Kernel 2 v7: ZERO-barrier streaming MFMA.
// Rounds 0-4 post-mortem: every LDS variant convoys on one vmcnt-drain +
// s_barrier per K-step (32x ~6000cy with ~200cy of work) -> ~1 TB/s, all
// pipes idle, time structure-invariant. Fix: remove the need for shared
// staging entirely.
//  - B operand: Yt stored fragment-native by y_kernel -> one coalesced
//    dwordx4 at base+lane*16 per (kc,ni) IS the fragment. No LDS, no pack.
//  - A operand: wave-PRIVATE double-buffered LDS tile [16][68] fp32,
//    K_STEP=64 (same-wave producer/consumer -> lgkmcnt only, no barrier).
//    Frag read (4*lcol+8*q)%32 -> 2-way, free. Global side: 16 rows x 64B
//    segments per instr.
//  - Pipeline: A staged 1 stage ahead, B prefetched 2 kc ahead (ring
//    bfr[2][4]) -> ~12 outstanding wave-loads, 16 independent waves/CU.
// Fragment k-indices (kc*32 + q*8), rsum, epilogue byte-identical to the
// verified kernels. LDS 34.8 KB/block -> 4 blocks/CU; grid 1024 resident.
// ---------------------------------------------------------------------------
__global__ __launch_bounds__(256, 4) void gcn_kernel(const float* __restrict__ adj,
                                                     const unsigned short* __restrict__ Yt,
                                                     const float* __restrict__ bias,
                                                     float* __restrict__ out) {
    __shared__ float Alds[4][2][16 * 68];

    const int tid  = threadIdx.x;
    const int lane = tid & 63;
    const int w    = tid >> 6;

    const int raw = blockIdx.x;
    const int bid = (raw & 7) * 128 + (raw >> 3);    // XCD-contiguous, bijective
    const int b   = bid >> 5;
    const int n0  = (bid & 31) * 32;

    const int lcol = lane & 15, q = lane >> 4;
    const int wm = (w & 1) * 16;                     // row half  (0 / 16)
    const int wn = (w >> 1) * 64;                    // col half  (0 / 64)

    // ---- A staging addresses (wave-private) ----
    const int arow = lane >> 2;                      // 0..15
    const int ac4  = (lane & 3) * 4;                 // fp32 col base
    const float* aSrc = adj + ((size_t)(b * NN + n0 + wm + arow)) * NN + ac4;
    float* aBuf0 = &Alds[w][0][arow * 68 + ac4];
    float* aBuf1 = &Alds[w][1][arow * 68 + ac4];
    const float* aRd0 = &Alds[w][0][lcol * 68];
    const float* aRd1 = &Alds[w][1][lcol * 68];

    // ---- B fragment-native base: + (kc*8 + ni)*512 shorts per fragment ----
    const unsigned short* bPtr =
        Yt + ((size_t)(b * 32) * 8 + (wn >> 4)) * 512 + (size_t)lane * 8;

    f32x4 acc[4] = {};
    float rsum = 0.f;

    float4 av[4];                                    // A stage in flight
    uint4  bfr[2][4];                                // B ring, 2 kc deep

    #define GLOADA(t_)                                                        \
        do { _Pragma("unroll")                                                \
            for (int i = 0; i < 4; ++i)                                       \
                av[i] = *(const float4*)(aSrc + (t_) * 64 + i * 16);          \
        } while (0)
    #define DSWRA(bufp)                                                       \
        do { _Pragma("unroll")                                                \
            for (int i = 0; i < 4; ++i)                                       \
                *(float4*)((bufp) + i * 16) = av[i];                          \
        } while (0)
    #define GLOADB(slot, kc_)                                                 \
        do { _Pragma("unroll")                                                \
            for (int ni = 0; ni < 4; ++ni)                                    \
                bfr[slot][ni] = *(const uint4*)(bPtr +                        \
                    ((size_t)((kc_) * 8 + ni)) * 512);                        \
        } while (0)
    #define KCSTEP(rdp, kcl, slot)                                            \
        do {                                                                  \
            const float4 f0 = *(const float4*)((rdp) + (kcl) * 32 + q * 8);   \
            const float4 f1 = *(const float4*)((rdp) + (kcl) * 32 + q * 8 + 4);\
            rsum += ((f0.x + f0.y) + (f0.z + f0.w))                           \
                  + ((f1.x + f1.y) + (f1.z + f1.w));                          \
            uint4 pk;                                                         \
            pk.x = pack2(f0.x, f0.y); pk.y = pack2(f0.z, f0.w);               \
            pk.z = pack2(f1.x, f1.y); pk.w = pack2(f1.z, f1.w);               \
            const bf16x8 a = *(const bf16x8*)&pk;                             \
            _Pragma("unroll")                                                 \
            for (int ni = 0; ni < 4; ++ni) {                                  \
                const bf16x8 bbf = *(const bf16x8*)&bfr[slot][ni];            \
                acc[ni] = __builtin_amdgcn_mfma_f32_16x16x32_bf16(            \
                    a, bbf, acc[ni], 0, 0, 0);                                \
            }                                                                 \
        } while (0)

    // prologue: stage 0 -> buf0; stage 1 in regs; B kc=0,1 in ring
    GLOADA(0);
    DSWRA(aBuf0);
    GLOADA(1);
    GLOADB(0, 0);
    GLOADB(1, 1);

    #pragma unroll 2
    for (int t = 0; t < 16; ++t) {
        float*       wrBuf = (t & 1) ? aBuf0 : aBuf1;   // stage t+1 -> buf (t+1)&1
        const float* rdBuf = (t & 1) ? aRd1  : aRd0;
        if (t < 15) DSWRA(wrBuf);
        if (t < 14) GLOADA(t + 2);
        KCSTEP(rdBuf, 0, 0);                            // kc = 2t
        if (t < 15) GLOADB(0, 2 * t + 2);
        KCSTEP(rdBuf, 1, 1);                            // kc = 2t+1
        if (t < 15) GLOADB(1, 2 * t + 3);
    }
    #undef GLOADA
    #undef DSWRA
    #undef GLOADB
    #undef KCSTEP

    // full row sums: lanes sharing lcol hold disjoint k-slices of row wm+lcol
    rsum += __shfl_xor(rsum, 16);
    rsum += __shfl_xor(rsum, 32);

    // D layout: col = lane&15 (o), row-in-tile = q*4 + r.
    // 1/rowsum for row wm+(rq+r): lane rq+r holds it (lcol = rq+r).
    const int rq = q * 4;
    float sc[4];
    #pragma unroll
    for (int r = 0; r < 4; ++r) sc[r] = 1.0f / __shfl(rsum, rq + r);

    float* outB = out + ((size_t)(b * NN + n0 + wm)) * FOUT;
    #pragma unroll
    for (int ni = 0; ni < 4; ++ni) {
        const float bc = bias[wn + ni * 16 + lcol];
        #pragma unroll
        for (int r = 0; r < 4; ++r) {
            float v = acc[ni][r] * sc[r] + bc;
            v = (v >= 0.f) ? v : 0.01f * v;
            outB[(size_t)(rq + r) * FOUT + wn + ni * 16 + lcol] = v;
        }
    }
}

extern "C" void kernel_launch(void* const* d_in, const int* in_sizes, int n_in,
                              void* d_out, int out_size, void* d_ws, size_t ws_size,
                              hipStream_t stream) {
    const float* node = (const float*)d_in[0];   // [32,1024,128]
    const float* adj  = (const float*)d_in[1];   // [32,1024,1024]
    const float* W    = (const float*)d_in[2];   // [128,128]
    const float* bias = (const float*)d_in[3];   // [128]
    float* out = (float*)d_out;                  // [32,1024,128] fp32
    unsigned short* Yt = (unsigned short*)d_ws;  // fragment-native, 8 MiB

    hipLaunchKernelGGL(y_kernel,   dim3(512),  dim3(256), 0, stream, node, W, Yt);
    hipLaunchKernelGGL(gcn_kernel, dim3(1024), dim3(256), 0, stream, adj, Yt, bias, out);
}

// Round 6
// 225.871 us; speedup vs baseline: 1.3239x; 1.3239x over previous
//
#include <hip/hip_runtime.h>
#include <cstdint>
#include <cstddef>

#define BB   32
#define NN   1024
#define FIN  128
#define FOUT 128

typedef __attribute__((ext_vector_type(8))) short bf16x8;
typedef __attribute__((ext_vector_type(4))) float f32x4;

__device__ __forceinline__ unsigned int f2bf(float f) {
    union { float f; unsigned int u; } v; v.f = f;
    unsigned int u = v.u;
    return (u + 0x7FFFu + ((u >> 16) & 1u)) >> 16;   // RNE fp32 -> bf16
}
__device__ __forceinline__ unsigned int pack2(float a, float b) {
    return f2bf(a) | (f2bf(b) << 16);
}

// async global -> LDS DMA, 16 B per lane; LDS dst is wave-uniform base,
// HW scatters lane i to base + i*16 (m97/m104 semantics)
__device__ __forceinline__ void load_lds16(const void* g, void* l) {
    __builtin_amdgcn_global_load_lds(
        (const __attribute__((address_space(1))) unsigned int*)g,
        (__attribute__((address_space(3))) unsigned int*)l, 16, 0, 0);
}

// ---------------------------------------------------------------------------
// Kernel 1: Yt[b][o][m] = sum_f node[b][m][f] * W[o][f]  (bf16, [B][FOUT][NN])
// (reverted to the multiply-verified round-0/3 version; ~3 us)
// ---------------------------------------------------------------------------
__global__ __launch_bounds__(256) void y_kernel(const float* __restrict__ node,
                                                const float* __restrict__ W,
                                                unsigned short* __restrict__ Yt) {
    __shared__ unsigned short Wlds[128 * 136];
    __shared__ unsigned short Nlds[64 * 136];

    const int tid = threadIdx.x;
    const int bid = blockIdx.x;
    const int b   = bid >> 4;
    const int m0  = (bid & 15) * 64;

    #pragma unroll
    for (int i = 0; i < 16; ++i) {
        const int idx = i * 256 + tid;
        const int row = idx >> 5;
        const int c   = (idx & 31) * 4;
        float4 v = ((const float4*)W)[idx];
        uint2 p; p.x = pack2(v.x, v.y); p.y = pack2(v.z, v.w);
        *(uint2*)&Wlds[row * 136 + c] = p;
    }
    {
        const float* base = node + ((size_t)b * NN + m0) * FIN;
        #pragma unroll
        for (int i = 0; i < 8; ++i) {
            const int idx = i * 256 + tid;
            const int row = idx >> 5;
            const int c   = (idx & 31) * 4;
            float4 v = *(const float4*)(base + row * FIN + c);
            uint2 p; p.x = pack2(v.x, v.y); p.y = pack2(v.z, v.w);
            *(uint2*)&Nlds[row * 136 + c] = p;
        }
    }
    __syncthreads();

    const int w = tid >> 6, lane = tid & 63;
    const int wo = w * 32;
    const int lcol = lane & 15, lk = (lane >> 4) * 8;

    f32x4 acc[2][4] = {};
    #pragma unroll
    for (int kc = 0; kc < 4; ++kc) {
        const int kof = kc * 32 + lk;
        bf16x8 a[2], bb[4];
        #pragma unroll
        for (int mi = 0; mi < 2; ++mi)
            a[mi] = *(const bf16x8*)&Wlds[(wo + mi*16 + lcol) * 136 + kof];
        #pragma unroll
        for (int ni = 0; ni < 4; ++ni)
            bb[ni] = *(const bf16x8*)&Nlds[(ni*16 + lcol) * 136 + kof];
        #pragma unroll
        for (int mi = 0; mi < 2; ++mi)
            #pragma unroll
            for (int ni = 0; ni < 4; ++ni)
                acc[mi][ni] = __builtin_amdgcn_mfma_f32_16x16x32_bf16(
                    a[mi], bb[ni], acc[mi][ni], 0, 0, 0);
    }
    __syncthreads();

    unsigned short* Ylds = Wlds;
    const int rq = (lane >> 4) * 4;
    #pragma unroll
    for (int mi = 0; mi < 2; ++mi)
        #pragma unroll
        for (int ni = 0; ni < 4; ++ni)
            #pragma unroll
            for (int r = 0; r < 4; ++r) {
                const int o = wo + mi * 16 + rq + r;
                const int m = ni * 16 + lcol;
                Ylds[o * 72 + m] = (unsigned short)f2bf(acc[mi][ni][r]);
            }
    __syncthreads();

    {
        const int oq = tid >> 3, c = (tid & 7) * 8;
        #pragma unroll
        for (int j = 0; j < 4; ++j) {
            const int o = oq + 32 * j;
            uint4 v = *(const uint4*)&Ylds[o * 72 + c];
            *(uint4*)(Yt + ((size_t)b * FOUT + o) * NN + m0 + c) = v;
        }
    }
}

// ---------------------------------------------------------------------------
// Kernel 2 v8: BM=128 tile to cut per-CU vmem traffic 1.9x.
// Rounds 0,2,3,4 all plateau at ~5 TB/s CU-side traffic (8.5 B/cy/CU ~= m13's
// 10.2 B/cy/CU streaming ceiling) regardless of structure -> the limiter is
// bytes crossing each CU, dominated by Yt re-read: (1024/BM)*256KB per batch.
// BM=32: 12 MB/batch (384 MB). BM=128: 6 MB/batch (213 MB) -> ~41 us at the
// same plateau. Round-5's reg-ring spilled (WRITE_SIZE 137 MB) -> reverted.
//   grid 256 (1 block/CU, XCD-bijective: 4 batches/XCD = 1 MB Yt in L2),
//   block 1024 = 16 waves (4 waves/SIMD, same per-SIMD TLP as round 3).
//   Per-wave shape IDENTICAL to round 3 (16 rows x 64 cols, acc[4], same
//   fragment k-indices / pack / rowsum / epilogue).
//   K_STEP=64, 16 steps, double-buffered 96 KB LDS; round-3 within-line
//   source swizzle; T4 counted vmcnt(3): each step's 3 DMA/wave prefetch
//   flies a full step before being waited on.
// ---------------------------------------------------------------------------
#define ABYTES 32768                 // A: [128][64] fp32
#define BBYTES 16384                 // B: [128][64] bf16
#define BUFB   (ABYTES + BBYTES)     // 48 KB per buffer

__global__ __launch_bounds__(1024, 4) void gcn_kernel(const float* __restrict__ adj,
                                                      const unsigned short* __restrict__ Yt,
                                                      const float* __restrict__ bias,
                                                      float* __restrict__ out) {
    __shared__ __align__(16) char smem[2 * BUFB];    // 96 KB

    const int tid  = threadIdx.x;
    const int lane = tid & 63;
    const int w    = tid >> 6;                        // 0..15

    const int raw = blockIdx.x;                       // grid 256
    const int bid = (raw & 7) * 32 + (raw >> 3);      // XCD-contiguous, bijective
    const int b   = bid >> 3;
    const int n0  = (bid & 7) * 128;

    const int lcol = lane & 15, q = lane >> 4;
    const int wm = (w & 7) * 16;                      // row sixteenth (0..112)
    const int wn = (w >> 3) * 64;                     // col half     (0 / 64)

    // ---- DMA source/dest (source carries within-line chunk swizzle) ----
    // A: 128 rows x 64 fp32 = 32 KB/step = 32 instrs; wave w does j=0,1.
    //    instr i = w*2+j covers rows i*4..i*4+3; lane l: row i*4+(l>>4),
    //    16B chunk c = l&15, fetched chunk g = (c&8) | ((c&7)^(row&7)).
    const float* aSrc[2];
    char*        aDst[2];
    #pragma unroll
    for (int j = 0; j < 2; ++j) {
        const int i  = w * 2 + j;
        const int rA = i * 4 + (lane >> 4);
        const int c  = lane & 15;
        const int g  = (c & 8) | ((c & 7) ^ (rA & 7));
        aSrc[j] = adj + ((size_t)(b * NN + n0 + rA)) * NN + g * 4;
        aDst[j] = smem + i * 1024;
    }
    // B: 128 rows x 64 bf16 = 16 KB/step = 16 instrs; wave w does one.
    //    rows o = w*8+(l>>3); chunk c = l&7; fetched g = c ^ (o&7).
    const unsigned short* bSrc;
    char* bDst;
    {
        const int o = w * 8 + (lane >> 3);
        const int c = lane & 7;
        const int g = c ^ (o & 7);
        bSrc = Yt + ((size_t)(b * FOUT + o)) * NN + g * 8;
        bDst = smem + ABYTES + w * 1024;
    }

    // ---- fragment read byte-offsets within a buffer (swizzle folded in) ----
    const int R = wm + lcol, keyR = R & 7;
    int offA[2][2], offB[2][4];
    #pragma unroll
    for (int kcl = 0; kcl < 2; ++kcl) {
        offA[kcl][0] = (R * 16 + kcl * 8 + ((2 * q)     ^ keyR)) * 16;
        offA[kcl][1] = (R * 16 + kcl * 8 + ((2 * q + 1) ^ keyR)) * 16;
        #pragma unroll
        for (int ni = 0; ni < 4; ++ni) {
            const int o = wn + ni * 16 + lcol;
            offB[kcl][ni] = ABYTES + (o * 8 + ((kcl * 4 + q) ^ (o & 7))) * 16;
        }
    }

    f32x4 acc[4] = {};
    float rsum = 0.f;

    #define STAGE(buf, s)                                                  \
        do {                                                               \
            load_lds16(aSrc[0] + (s) * 64, aDst[0] + (buf) * BUFB);        \
            load_lds16(aSrc[1] + (s) * 64, aDst[1] + (buf) * BUFB);        \
            load_lds16(bSrc    + (s) * 64, bDst    + (buf) * BUFB);        \
        } while (0)

    #define COMPUTE(buf)                                                   \
        do {                                                               \
            const char* base = smem + (buf) * BUFB;                        \
            _Pragma("unroll")                                              \
            for (int kcl = 0; kcl < 2; ++kcl) {                            \
                const float4 f0 = *(const float4*)(base + offA[kcl][0]);   \
                const float4 f1 = *(const float4*)(base + offA[kcl][1]);   \
                rsum += ((f0.x + f0.y) + (f0.z + f0.w))                    \
                      + ((f1.x + f1.y) + (f1.z + f1.w));                   \
                uint4 pk;                                                  \
                pk.x = pack2(f0.x, f0.y); pk.y = pack2(f0.z, f0.w);        \
                pk.z = pack2(f1.x, f1.y); pk.w = pack2(f1.z, f1.w);        \
                const bf16x8 a = *(const bf16x8*)&pk;                      \
                _Pragma("unroll")                                          \
                for (int ni = 0; ni < 4; ++ni) {                           \
                    const bf16x8 bbf = *(const bf16x8*)(base + offB[kcl][ni]); \
                    acc[ni] = __builtin_amdgcn_mfma_f32_16x16x32_bf16(     \
                        a, bbf, acc[ni], 0, 0, 0);                         \
                }                                                          \
            }                                                              \
        } while (0)

    // prologue: stage step 0 into buf0
    STAGE(0, 0);
    asm volatile("s_waitcnt vmcnt(0)" ::: "memory");
    __builtin_amdgcn_s_barrier();

    #pragma unroll 2
    for (int t = 0; t < 16; ++t) {
        const int cur = t & 1, nxt = cur ^ 1;
        if (t < 15) {
            STAGE(nxt, t + 1);                         // prefetch next step
            asm volatile("s_waitcnt vmcnt(3)" ::: "memory");  // step t's 3 done
        } else {
            asm volatile("s_waitcnt vmcnt(0)" ::: "memory");
        }
        __builtin_amdgcn_s_barrier();                  // all waves: cur visible
        COMPUTE(cur);
        if (t < 15) __builtin_amdgcn_s_barrier();      // done reading cur before
                                                       // next iter overwrites it
    }
    #undef STAGE
    #undef COMPUTE

    // full row sums: lanes sharing lcol hold disjoint k-slices of row wm+lcol
    rsum += __shfl_xor(rsum, 16);
    rsum += __shfl_xor(rsum, 32);

    // D layout: col = lane&15 (o), row-in-tile = q*4 + r.
    // 1/rowsum for row wm+(rq+r): lane rq+r holds it (lcol = rq+r).
    const int rq = q * 4;
    float sc[4];
    #pragma unroll
    for (int r = 0; r < 4; ++r) sc[r] = 1.0f / __shfl(rsum, rq + r);

    float* outB = out + ((size_t)(b * NN + n0 + wm)) * FOUT;
    #pragma unroll
    for (int ni = 0; ni < 4; ++ni) {
        const float bc = bias[wn + ni * 16 + lcol];
        #pragma unroll
        for (int r = 0; r < 4; ++r) {
            float v = acc[ni][r] * sc[r] + bc;
            v = (v >= 0.f) ? v : 0.01f * v;
            outB[(size_t)(rq + r) * FOUT + wn + ni * 16 + lcol] = v;
        }
    }
}

extern "C" void kernel_launch(void* const* d_in, const int* in_sizes, int n_in,
                              void* d_out, int out_size, void* d_ws, size_t ws_size,
                              hipStream_t stream) {
    const float* node = (const float*)d_in[0];   // [32,1024,128]
    const float* adj  = (const float*)d_in[1];   // [32,1024,1024]
    const float* W    = (const float*)d_in[2];   // [128,128]
    const float* bias = (const float*)d_in[3];   // [128]
    float* out = (float*)d_out;                  // [32,1024,128] fp32
    unsigned short* Yt = (unsigned short*)d_ws;  // [32,128,1024] bf16 = 8 MiB

    hipLaunchKernelGGL(y_kernel,   dim3(512), dim3(256),  0, stream, node, W, Yt);
    hipLaunchKernelGGL(gcn_kernel, dim3(256), dim3(1024), 0, stream, adj, Yt, bias, out);
}